// Round 3
// baseline (487.494 us; speedup 1.0000x reference)
//
#include <hip/hip_runtime.h>

// ---------------------------------------------------------------------------
// Transformer block (B=2, T=2048, C=1024, H=16) on MI355X, bf16 MFMA.
// Reference's quirky reshape: q/k/v = (B,T,C).reshape(B,H,T,hd) DIRECTLY
// => head h attends over xp rows [h*128,(h+1)*128) reinterpreted as 2048
// pseudo-times x 64 ch:  q[b,h,tau,d] = xp[b, h*128 + tau/16, (tau%16)*64+d].
// Output reshape IS standard: y_out[b, tau, h*64+d] = y[b,h,tau,d].
// Workspace layout (88 MB):
//   [0,8M) xb | [8M,32M) xp | [0,32M) h (reuse) | [32M,40M) y
//   [40M,56M) x1 f32 | [56M,64M) x1 bf16 | [64M,88M) transposed weights
// ---------------------------------------------------------------------------

typedef __attribute__((ext_vector_type(8))) short  bf16x8;
typedef __attribute__((ext_vector_type(4))) float  f32x4;
typedef __attribute__((ext_vector_type(8))) unsigned short u16x8;

__device__ __forceinline__ unsigned short bfu(float f) {
    union { float f; unsigned int u; } c; c.f = f;
    unsigned int u = c.u;
    unsigned int r = (u + 0x7fffu + ((u >> 16) & 1u)) >> 16;
    return (unsigned short)r;
}

__device__ __forceinline__ void gload_lds16(const void* g, void* l) {
    __builtin_amdgcn_global_load_lds(
        (const __attribute__((address_space(1))) void*)g,
        (__attribute__((address_space(3))) void*)l, 16, 0, 0);
}

// --------------------------- fp32 -> bf16 convert ---------------------------
__global__ __launch_bounds__(256) void cvt_bf16(const float* __restrict__ in,
                                                unsigned short* __restrict__ out) {
    size_t i = (size_t)blockIdx.x * 256 + threadIdx.x;
    const float4* p = (const float4*)in;
    float4 a = p[2 * i], b = p[2 * i + 1];
    u16x8 v;
    v[0] = bfu(a.x); v[1] = bfu(a.y); v[2] = bfu(a.z); v[3] = bfu(a.w);
    v[4] = bfu(b.x); v[5] = bfu(b.y); v[6] = bfu(b.z); v[7] = bfu(b.w);
    *(u16x8*)(out + 8 * i) = v;
}

// ----------------- weight transpose + convert: W[K][N] -> Wt[N][K] ----------
__global__ __launch_bounds__(256) void wtrans(const float* __restrict__ W,
                                              unsigned short* __restrict__ Wt,
                                              int K, int N) {
    __shared__ float tile[32][33];
    int n0 = blockIdx.x * 32, k0 = blockIdx.y * 32;
    int tx = threadIdx.x & 31, ty = threadIdx.x >> 5;  // ty in 0..7
#pragma unroll
    for (int r = 0; r < 32; r += 8)
        tile[ty + r][tx] = W[(size_t)(k0 + ty + r) * N + n0 + tx];
    __syncthreads();
#pragma unroll
    for (int r = 0; r < 32; r += 8)
        Wt[(size_t)(n0 + ty + r) * K + k0 + tx] = bfu(tile[tx][ty + r]);
}

// --------------------------- GEMM: C = A @ Bt^T -----------------------------
// m97 structure: 128x128 tile, BK=32, 4 waves (2x2), 4x4 16x16x32 frags/wave.
// EPI: 0 = +bias -> bf16 | 1 = +bias+res -> f32 AND bf16 | 2 = +bias,gelu ->
// bf16 | 3 = +bias+res -> f32
template <int EPI>
__global__ __launch_bounds__(256) void gemm_bf16(
    const unsigned short* __restrict__ A, const unsigned short* __restrict__ Bt,
    const float* __restrict__ bias, const float* __restrict__ res,
    unsigned short* __restrict__ outb, float* __restrict__ outf,
    int M, int N, int K) {
    __shared__ __align__(16) unsigned short As[128 * 32];
    __shared__ __align__(16) unsigned short Bs[128 * 32];
    const int t = threadIdx.x;
    const int l = t & 63, w = t >> 6;
    const int lr = l & 15, lg = l >> 4;
    const int brow = blockIdx.y * 128, bcol = blockIdx.x * 128;
    const int wr = (w >> 1) * 64, wc = (w & 1) * 64;

    f32x4 acc[4][4];
#pragma unroll
    for (int m = 0; m < 4; ++m)
#pragma unroll
        for (int n = 0; n < 4; ++n) acc[m][n] = (f32x4){0.f, 0.f, 0.f, 0.f};

    const int ar = t >> 2, ac = (t & 3) * 8;
    const size_t Abase = (size_t)(brow + ar) * K + ac;
    const size_t Bbase = (size_t)(bcol + ar) * K + ac;
    char* la = (char*)As + w * 1024;
    char* lb = (char*)Bs + w * 1024;

    for (int kt = 0; kt < K; kt += 32) {
        gload_lds16(A + Abase + kt, la);
        gload_lds16(A + Abase + (size_t)64 * K + kt, la + 4096);
        gload_lds16(Bt + Bbase + kt, lb);
        gload_lds16(Bt + Bbase + (size_t)64 * K + kt, lb + 4096);
        __syncthreads();

        bf16x8 af[4], bfr[4];
#pragma unroll
        for (int m = 0; m < 4; ++m)
            af[m] = *(const bf16x8*)(As + (wr + m * 16 + lr) * 32 + lg * 8);
#pragma unroll
        for (int n = 0; n < 4; ++n)
            bfr[n] = *(const bf16x8*)(Bs + (wc + n * 16 + lr) * 32 + lg * 8);
#pragma unroll
        for (int m = 0; m < 4; ++m)
#pragma unroll
            for (int n = 0; n < 4; ++n)
                acc[m][n] = __builtin_amdgcn_mfma_f32_16x16x32_bf16(
                    af[m], bfr[n], acc[m][n], 0, 0, 0);
        __syncthreads();
    }

    float bv[4];
#pragma unroll
    for (int n = 0; n < 4; ++n) bv[n] = bias[bcol + wc + n * 16 + lr];
#pragma unroll
    for (int m = 0; m < 4; ++m) {
#pragma unroll
        for (int r = 0; r < 4; ++r) {
            const int row = brow + wr + m * 16 + lg * 4 + r;
#pragma unroll
            for (int n = 0; n < 4; ++n) {
                const int col = bcol + wc + n * 16 + lr;
                const size_t idx = (size_t)row * N + col;
                float v = acc[m][n][r] + bv[n];
                if constexpr (EPI == 0) {
                    outb[idx] = bfu(v);
                } else if constexpr (EPI == 1) {
                    v += res[idx];
                    outf[idx] = v;
                    outb[idx] = bfu(v);
                } else if constexpr (EPI == 2) {
                    float a = 0.7978845608f * (v + 0.044715f * v * v * v);
                    float g = v / (1.0f + __expf(-2.0f * a));  // v*sigmoid(2a)
                    outb[idx] = bfu(g);
                } else {
                    v += res[idx];
                    outf[idx] = v;
                }
            }
        }
    }
}

// ------------------------------ flash attention -----------------------------
// Re-grid for occupancy: 1024 blocks x 2 waves (128 thr); block = (b,h) x 64
// pseudo-q rows; wave = 32 q. 18.4 KB LDS -> 8 blocks/CU -> whole grid
// co-resident (16 waves/CU), stalls overlap across blocks, causal imbalance
// self-levels. KV tile 64. K-frags direct from global (L1-shared by 2 waves).
// V staged transposed to padded LDS [64][72] with permuted contraction s
// (kv = (s%4)*16 + s/4) shared with the P packing -> b64 P stores, b128 reads.
// Softmax in exp2 domain: QK scale folded with log2e into one multiply.
__global__ __launch_bounds__(128) void attn(const unsigned short* __restrict__ xp,
                                            unsigned short* __restrict__ y) {
    __shared__ __align__(16) unsigned short Vt[64 * 72];
    __shared__ __align__(16) unsigned short Pl[2][32 * 72];
    const int t = threadIdx.x;
    const int l = t & 63, w = t >> 6;          // w in {0,1}
    const int lr = l & 15, lg = l >> 4;
    const int bh = blockIdx.x >> 5;
    const int u = blockIdx.x & 31;
    const int qt = (u & 1) ? (31 - (u >> 1)) : (u >> 1);  // big+small pairing
    const int b = bh >> 4, h = bh & 15;
    const size_t hb = ((size_t)b * 2048 + h * 128) * 3072;  // head block base
    const size_t rowb = (size_t)b * 2048;                    // output row base
    const int q0 = qt * 64 + w * 32;

    // hoist Q fragments: tau_q = q0 + mq*16 + lr -> xp row (q0>>4)+mq, ch lr*64
    bf16x8 qf[2][2];
#pragma unroll
    for (int mq = 0; mq < 2; ++mq)
#pragma unroll
        for (int kk = 0; kk < 2; ++kk)
            qf[mq][kk] = *(const bf16x8*)(xp + hb + (size_t)((q0 >> 4) + mq) * 3072 +
                                          lr * 64 + kk * 32 + lg * 8);

    f32x4 o[2][4];
    float mx[2][4], ls[2][4];
#pragma unroll
    for (int mq = 0; mq < 2; ++mq)
#pragma unroll
        for (int n = 0; n < 4; ++n) o[mq][n] = (f32x4){0.f, 0.f, 0.f, 0.f};
#pragma unroll
    for (int mq = 0; mq < 2; ++mq)
#pragma unroll
        for (int r = 0; r < 4; ++r) { mx[mq][r] = -1e30f; ls[mq][r] = 0.f; }

    const int qmaxw = q0 + 31;
    const int ntiles = qt + 1;
    const int m32 = t & 31;  // d-pair index for V staging
    const int cc = t >> 5;   // 0..3
    const float SC = 0.18033688f;  // (1/sqrt(64)) * log2(e)

    for (int j = 0; j < ntiles; ++j) {
        const int kv0 = j * 64;
        __syncthreads();  // prior PV reads of Vt complete
        // ---- stage V transposed: Vt[d][s], s=c*4+n, tau_v = kv0 + n*16 + c
#pragma unroll
        for (int it = 0; it < 4; ++it) {
            const int c = cc + it * 4;
            unsigned int xv[4];
#pragma unroll
            for (int n = 0; n < 4; ++n)
                xv[n] = *(const unsigned int*)(xp + hb + 2048 +
                                               (size_t)((kv0 >> 4) + n) * 3072 +
                                               c * 64 + 2 * m32);
            unsigned int lo0 = (xv[0] & 0xffffu) | (xv[1] << 16);
            unsigned int lo1 = (xv[2] & 0xffffu) | (xv[3] << 16);
            unsigned int hi0 = (xv[0] >> 16) | (xv[1] & 0xffff0000u);
            unsigned int hi1 = (xv[2] >> 16) | (xv[3] & 0xffff0000u);
            *(uint2*)(Vt + (2 * m32) * 72 + c * 4) = make_uint2(lo0, lo1);
            *(uint2*)(Vt + (2 * m32 + 1) * 72 + c * 4) = make_uint2(hi0, hi1);
        }
        __syncthreads();  // Vt staged

        {
            // ---- S = Q @ K^T; tau_k = kv0 + n*16 + lr
            f32x4 s[2][4];
#pragma unroll
            for (int mq = 0; mq < 2; ++mq)
#pragma unroll
                for (int n = 0; n < 4; ++n) s[mq][n] = (f32x4){0.f, 0.f, 0.f, 0.f};
#pragma unroll
            for (int kk = 0; kk < 2; ++kk)
#pragma unroll
                for (int n = 0; n < 4; ++n) {
                    bf16x8 kf = *(const bf16x8*)(xp + hb + 1024 +
                                                 (size_t)((kv0 >> 4) + n) * 3072 +
                                                 lr * 64 + kk * 32 + lg * 8);
#pragma unroll
                    for (int mq = 0; mq < 2; ++mq)
                        s[mq][n] = __builtin_amdgcn_mfma_f32_16x16x32_bf16(
                            qf[mq][kk], kf, s[mq][n], 0, 0, 0);
                }
            // ---- scale (exp2 domain) + causal mask (row=lg*4+r, col=lr)
            const bool needMask = (kv0 + 63) > q0;
#pragma unroll
            for (int mq = 0; mq < 2; ++mq)
#pragma unroll
                for (int n = 0; n < 4; ++n) {
                    s[mq][n] = s[mq][n] * SC;
                    if (needMask) {
                        const int col = kv0 + n * 16 + lr;
#pragma unroll
                        for (int r = 0; r < 4; ++r) {
                            const int row = q0 + mq * 16 + lg * 4 + r;
                            if (col > row) s[mq][n][r] = -1e30f;
                        }
                    }
                }
            // ---- row max over n + 16-lane group
            float rmx[2][4], corr[2][4], rsum[2][4];
#pragma unroll
            for (int mq = 0; mq < 2; ++mq)
#pragma unroll
                for (int r = 0; r < 4; ++r)
                    rmx[mq][r] = fmaxf(fmaxf(s[mq][0][r], s[mq][1][r]),
                                       fmaxf(s[mq][2][r], s[mq][3][r]));
#pragma unroll
            for (int d = 1; d < 16; d <<= 1)
#pragma unroll
                for (int mq = 0; mq < 2; ++mq)
#pragma unroll
                    for (int r = 0; r < 4; ++r)
                        rmx[mq][r] = fmaxf(rmx[mq][r], __shfl_xor(rmx[mq][r], d, 64));
            // ---- online softmax update (base-2)
#pragma unroll
            for (int mq = 0; mq < 2; ++mq)
#pragma unroll
                for (int r = 0; r < 4; ++r) {
                    float mn = fmaxf(mx[mq][r], rmx[mq][r]);
                    corr[mq][r] = exp2f(mx[mq][r] - mn);
                    mx[mq][r] = mn;
                }
#pragma unroll
            for (int mq = 0; mq < 2; ++mq)
#pragma unroll
                for (int n = 0; n < 4; ++n)
#pragma unroll
                    for (int r = 0; r < 4; ++r)
                        s[mq][n][r] = exp2f(s[mq][n][r] - mx[mq][r]);
#pragma unroll
            for (int mq = 0; mq < 2; ++mq)
#pragma unroll
                for (int r = 0; r < 4; ++r)
                    rsum[mq][r] = s[mq][0][r] + s[mq][1][r] + s[mq][2][r] + s[mq][3][r];
#pragma unroll
            for (int d = 1; d < 16; d <<= 1)
#pragma unroll
                for (int mq = 0; mq < 2; ++mq)
#pragma unroll
                    for (int r = 0; r < 4; ++r)
                        rsum[mq][r] += __shfl_xor(rsum[mq][r], d, 64);
#pragma unroll
            for (int mq = 0; mq < 2; ++mq)
#pragma unroll
                for (int r = 0; r < 4; ++r)
                    ls[mq][r] = ls[mq][r] * corr[mq][r] + rsum[mq][r];
#pragma unroll
            for (int mq = 0; mq < 2; ++mq)
#pragma unroll
                for (int nd = 0; nd < 4; ++nd)
#pragma unroll
                    for (int r = 0; r < 4; ++r) o[mq][nd][r] *= corr[mq][r];
            // ---- pack P -> per-wave LDS, permuted col s = lr*4 + n (b64)
#pragma unroll
            for (int mq = 0; mq < 2; ++mq)
#pragma unroll
                for (int r = 0; r < 4; ++r) {
                    const int row = mq * 16 + lg * 4 + r;
                    unsigned int u0 = (unsigned)bfu(s[mq][0][r]) |
                                      ((unsigned)bfu(s[mq][1][r]) << 16);
                    unsigned int u1 = (unsigned)bfu(s[mq][2][r]) |
                                      ((unsigned)bfu(s[mq][3][r]) << 16);
                    *(uint2*)(&Pl[w][row * 72 + lr * 4]) = make_uint2(u0, u1);
                }
            asm volatile("s_waitcnt lgkmcnt(0)" ::: "memory");  // wave-internal RAW
            __builtin_amdgcn_sched_barrier(0);
            // ---- O += P @ V (both in permuted-s contraction order)
#pragma unroll
            for (int kk = 0; kk < 2; ++kk) {
                bf16x8 pa[2];
                pa[0] = *(const bf16x8*)(&Pl[w][(lr) * 72 + kk * 32 + lg * 8]);
                pa[1] = *(const bf16x8*)(&Pl[w][(16 + lr) * 72 + kk * 32 + lg * 8]);
#pragma unroll
                for (int nd = 0; nd < 4; ++nd) {
                    bf16x8 vb = *(const bf16x8*)(Vt + (nd * 16 + lr) * 72 + kk * 32 + lg * 8);
                    o[0][nd] = __builtin_amdgcn_mfma_f32_16x16x32_bf16(pa[0], vb, o[0][nd], 0, 0, 0);
                    o[1][nd] = __builtin_amdgcn_mfma_f32_16x16x32_bf16(pa[1], vb, o[1][nd], 0, 0, 0);
                }
            }
        }
    }
    // ---- normalize + store: y[b, tau, h*64 + d] (standard output reshape)
#pragma unroll
    for (int mq = 0; mq < 2; ++mq)
#pragma unroll
        for (int r = 0; r < 4; ++r) {
            const float inv = 1.0f / ls[mq][r];
            const size_t row = rowb + q0 + mq * 16 + lg * 4 + r;
#pragma unroll
            for (int nd = 0; nd < 4; ++nd)
                y[row * 1024 + h * 64 + nd * 16 + lr] = bfu(o[mq][nd][r] * inv);
        }
}

// ------------------------------- launcher -----------------------------------
extern "C" void kernel_launch(void* const* d_in, const int* in_sizes, int n_in,
                              void* d_out, int out_size, void* d_ws, size_t ws_size,
                              hipStream_t stream) {
    const float* x     = (const float*)d_in[0];
    const float* Wqkv  = (const float*)d_in[1];
    const float* bqkv  = (const float*)d_in[2];
    const float* Wo    = (const float*)d_in[3];
    const float* bo    = (const float*)d_in[4];
    const float* Wfc   = (const float*)d_in[5];
    const float* bfc   = (const float*)d_in[6];
    const float* Wproj = (const float*)d_in[7];
    const float* bproj = (const float*)d_in[8];
    float* out = (float*)d_out;

    char* p = (char*)d_ws;
    unsigned short* xb     = (unsigned short*)(p);
    unsigned short* xpb    = (unsigned short*)(p + (8ull << 20));
    unsigned short* hbuf   = (unsigned short*)(p);              // reuses xb+xp
    unsigned short* ybuf   = (unsigned short*)(p + (32ull << 20));
    float*          x1     = (float*)(p + (40ull << 20));
    unsigned short* x1b    = (unsigned short*)(p + (56ull << 20));
    unsigned short* WqkvT  = (unsigned short*)(p + (64ull << 20));
    unsigned short* WoT    = (unsigned short*)(p + (70ull << 20));
    unsigned short* WfcT   = (unsigned short*)(p + (72ull << 20));
    unsigned short* WprojT = (unsigned short*)(p + (80ull << 20));

    cvt_bf16<<<dim3(2048), 256, 0, stream>>>(x, xb);
    wtrans<<<dim3(96, 32), 256, 0, stream>>>(Wqkv, WqkvT, 1024, 3072);
    wtrans<<<dim3(32, 32), 256, 0, stream>>>(Wo, WoT, 1024, 1024);
    wtrans<<<dim3(128, 32), 256, 0, stream>>>(Wfc, WfcT, 1024, 4096);
    wtrans<<<dim3(32, 128), 256, 0, stream>>>(Wproj, WprojT, 4096, 1024);

    // xp = x @ Wqkv + bqkv
    gemm_bf16<0><<<dim3(24, 32), 256, 0, stream>>>(xb, WqkvT, bqkv, nullptr,
                                                   xpb, nullptr, 4096, 3072, 1024);
    // y = attention(xp)  (reshape-aliased heads; 1024 co-resident blocks)
    attn<<<dim3(1024), 128, 0, stream>>>(xpb, ybuf);
    // x1 = x + y @ Wo + bo
    gemm_bf16<1><<<dim3(8, 32), 256, 0, stream>>>(ybuf, WoT, bo, x,
                                                  x1b, x1, 4096, 1024, 1024);
    // h = gelu(x1 @ Wfc + bfc)
    gemm_bf16<2><<<dim3(32, 32), 256, 0, stream>>>(x1b, WfcT, bfc, nullptr,
                                                   hbuf, nullptr, 4096, 4096, 1024);
    // out = x1 + h @ Wproj + bproj
    gemm_bf16<3><<<dim3(8, 32), 256, 0, stream>>>(hbuf, WprojT, bproj, x1,
                                                  nullptr, out, 4096, 1024, 4096);
}

// Round 6
// 460.091 us; speedup vs baseline: 1.0596x; 1.0596x over previous
//
#include <hip/hip_runtime.h>

// ---------------------------------------------------------------------------
// Transformer block (B=2, T=2048, C=1024, H=16) on MI355X, bf16 MFMA.
// Reference's quirky reshape: q/k/v = (B,T,C).reshape(B,H,T,hd) DIRECTLY
// => head h attends over xp rows [h*128,(h+1)*128) reinterpreted as 2048
// pseudo-times x 64 ch:  q[b,h,tau,d] = xp[b, h*128 + tau/16, (tau%16)*64+d].
// Output reshape IS standard: y_out[b, tau, h*64+d] = y[b,h,tau,d].
// Workspace layout (88 MB):
//   [0,8M) xb | [8M,32M) xp | [0,32M) h (reuse) | [32M,40M) y
//   [40M,56M) x1 f32 | [56M,64M) x1 bf16 | [64M,88M) transposed weights
// ---------------------------------------------------------------------------

typedef __attribute__((ext_vector_type(8))) short  bf16x8;
typedef __attribute__((ext_vector_type(4))) float  f32x4;
typedef __attribute__((ext_vector_type(8))) unsigned short u16x8;

__device__ __forceinline__ unsigned short bfu(float f) {
    union { float f; unsigned int u; } c; c.f = f;
    unsigned int u = c.u;
    unsigned int r = (u + 0x7fffu + ((u >> 16) & 1u)) >> 16;
    return (unsigned short)r;
}

__device__ __forceinline__ void gload_lds16(const void* g, void* l) {
    __builtin_amdgcn_global_load_lds(
        (const __attribute__((address_space(1))) void*)g,
        (__attribute__((address_space(3))) void*)l, 16, 0, 0);
}

// --------------------------- fp32 -> bf16 convert ---------------------------
__global__ __launch_bounds__(256) void cvt_bf16(const float* __restrict__ in,
                                                unsigned short* __restrict__ out) {
    size_t i = (size_t)blockIdx.x * 256 + threadIdx.x;
    const float4* p = (const float4*)in;
    float4 a = p[2 * i], b = p[2 * i + 1];
    u16x8 v;
    v[0] = bfu(a.x); v[1] = bfu(a.y); v[2] = bfu(a.z); v[3] = bfu(a.w);
    v[4] = bfu(b.x); v[5] = bfu(b.y); v[6] = bfu(b.z); v[7] = bfu(b.w);
    *(u16x8*)(out + 8 * i) = v;
}

// ----------------- weight transpose + convert: W[K][N] -> Wt[N][K] ----------
__global__ __launch_bounds__(256) void wtrans(const float* __restrict__ W,
                                              unsigned short* __restrict__ Wt,
                                              int K, int N) {
    __shared__ float tile[32][33];
    int n0 = blockIdx.x * 32, k0 = blockIdx.y * 32;
    int tx = threadIdx.x & 31, ty = threadIdx.x >> 5;  // ty in 0..7
#pragma unroll
    for (int r = 0; r < 32; r += 8)
        tile[ty + r][tx] = W[(size_t)(k0 + ty + r) * N + n0 + tx];
    __syncthreads();
#pragma unroll
    for (int r = 0; r < 32; r += 8)
        Wt[(size_t)(n0 + ty + r) * K + k0 + tx] = bfu(tile[tx][ty + r]);
}

// --------------------------- GEMM: C = A @ Bt^T -----------------------------
// m97 structure: 128x128 tile, BK=32, 4 waves (2x2), 4x4 16x16x32 frags/wave.
// EPI: 0 = +bias -> bf16 | 1 = +bias+res -> f32 AND bf16 | 2 = +bias,gelu ->
// bf16 | 3 = +bias+res -> f32
template <int EPI>
__global__ __launch_bounds__(256) void gemm_bf16(
    const unsigned short* __restrict__ A, const unsigned short* __restrict__ Bt,
    const float* __restrict__ bias, const float* __restrict__ res,
    unsigned short* __restrict__ outb, float* __restrict__ outf,
    int M, int N, int K) {
    __shared__ __align__(16) unsigned short As[128 * 32];
    __shared__ __align__(16) unsigned short Bs[128 * 32];
    const int t = threadIdx.x;
    const int l = t & 63, w = t >> 6;
    const int lr = l & 15, lg = l >> 4;
    const int brow = blockIdx.y * 128, bcol = blockIdx.x * 128;
    const int wr = (w >> 1) * 64, wc = (w & 1) * 64;

    f32x4 acc[4][4];
#pragma unroll
    for (int m = 0; m < 4; ++m)
#pragma unroll
        for (int n = 0; n < 4; ++n) acc[m][n] = (f32x4){0.f, 0.f, 0.f, 0.f};

    const int ar = t >> 2, ac = (t & 3) * 8;
    const size_t Abase = (size_t)(brow + ar) * K + ac;
    const size_t Bbase = (size_t)(bcol + ar) * K + ac;
    char* la = (char*)As + w * 1024;
    char* lb = (char*)Bs + w * 1024;

    for (int kt = 0; kt < K; kt += 32) {
        gload_lds16(A + Abase + kt, la);
        gload_lds16(A + Abase + (size_t)64 * K + kt, la + 4096);
        gload_lds16(Bt + Bbase + kt, lb);
        gload_lds16(Bt + Bbase + (size_t)64 * K + kt, lb + 4096);
        __syncthreads();

        bf16x8 af[4], bfr[4];
#pragma unroll
        for (int m = 0; m < 4; ++m)
            af[m] = *(const bf16x8*)(As + (wr + m * 16 + lr) * 32 + lg * 8);
#pragma unroll
        for (int n = 0; n < 4; ++n)
            bfr[n] = *(const bf16x8*)(Bs + (wc + n * 16 + lr) * 32 + lg * 8);
#pragma unroll
        for (int m = 0; m < 4; ++m)
#pragma unroll
            for (int n = 0; n < 4; ++n)
                acc[m][n] = __builtin_amdgcn_mfma_f32_16x16x32_bf16(
                    af[m], bfr[n], acc[m][n], 0, 0, 0);
        __syncthreads();
    }

    float bv[4];
#pragma unroll
    for (int n = 0; n < 4; ++n) bv[n] = bias[bcol + wc + n * 16 + lr];
#pragma unroll
    for (int m = 0; m < 4; ++m) {
#pragma unroll
        for (int r = 0; r < 4; ++r) {
            const int row = brow + wr + m * 16 + lg * 4 + r;
#pragma unroll
            for (int n = 0; n < 4; ++n) {
                const int col = bcol + wc + n * 16 + lr;
                const size_t idx = (size_t)row * N + col;
                float v = acc[m][n][r] + bv[n];
                if constexpr (EPI == 0) {
                    outb[idx] = bfu(v);
                } else if constexpr (EPI == 1) {
                    v += res[idx];
                    outf[idx] = v;
                    outb[idx] = bfu(v);
                } else if constexpr (EPI == 2) {
                    float a = 0.7978845608f * (v + 0.044715f * v * v * v);
                    float g = v / (1.0f + __expf(-2.0f * a));  // v*sigmoid(2a)
                    outb[idx] = bfu(g);
                } else {
                    v += res[idx];
                    outf[idx] = v;
                }
            }
        }
    }
}

// ------------------------------ flash attention -----------------------------
// KV-split flash attention. Block = 512 thr = 8 WAVES (round-4 bug: this was
// launched with 256 thr = 4 waves, so kv-groups 2,3 never existed and the
// merge read unwritten LDS). Wave w: qsub s=w&1 (32 rows), kv-group g=w>>1
// (g in 0..3). Group g runs tiles j = g, g+4, ... into its own Vt[g]; trip
// count ceil((qt+1)/4) is block-uniform so barriers are legal. End: 2 pairwise
// (o,m,l) merge rounds through LDS. Worst serial depth 32 -> 8 tiles.
// Heavy-qt blocks launch first (LPT). 72KB LDS -> 2 blocks/CU, 16 waves/CU.
__global__ __launch_bounds__(512, 4) void attn(const unsigned short* __restrict__ xp,
                                               unsigned short* __restrict__ y) {
    __shared__ __align__(16) char smem[73728];
    // tile-loop layout: Vt[4][64*72] u16 (36864B) + Pl[8][32*72] u16 (36864B)
    // merge layout:     buf[4][64 lanes][52 f32] (53248B), overlaid
    const int t = threadIdx.x;
    const int l = t & 63, w = t >> 6;          // 8 waves (512 threads)
    const int s = w & 1, g = w >> 1;           // qsub, kv-group
    const int lr = l & 15, lg = l >> 4;
    const int qt = 31 - (blockIdx.x >> 5);     // heavy blocks first (LPT)
    const int bh = blockIdx.x & 31;
    const int b = bh >> 4, h = bh & 15;
    const size_t hb = ((size_t)b * 2048 + h * 128) * 3072;  // head block base
    const size_t rowb = (size_t)b * 2048;                    // output row base
    const int q0 = qt * 64;
    const int qmin = q0 + s * 32;

    unsigned short* Vtg = (unsigned short*)smem + g * (64 * 72);
    unsigned short* Plw = (unsigned short*)(smem + 36864) + w * (32 * 72);

    // hoist Q fragments: tau_q = qmin + mq*16 + lr -> xp row (qmin>>4)+mq
    bf16x8 qf[2][2];
#pragma unroll
    for (int mq = 0; mq < 2; ++mq)
#pragma unroll
        for (int kk = 0; kk < 2; ++kk)
            qf[mq][kk] = *(const bf16x8*)(xp + hb + (size_t)((qmin >> 4) + mq) * 3072 +
                                          lr * 64 + kk * 32 + lg * 8);

    f32x4 o[2][4];
    float mx[2][4], ls[2][4];
#pragma unroll
    for (int mq = 0; mq < 2; ++mq)
#pragma unroll
        for (int n = 0; n < 4; ++n) o[mq][n] = (f32x4){0.f, 0.f, 0.f, 0.f};
#pragma unroll
    for (int mq = 0; mq < 2; ++mq)
#pragma unroll
        for (int r = 0; r < 4; ++r) { mx[mq][r] = -1e30f; ls[mq][r] = 0.f; }

    const int ntiles = qt + 1;
    const int niter = (qt + 4) >> 2;           // ceil(ntiles/4), block-uniform
    const int tg = s * 64 + l;                  // thread index within kv-group
    const int m32 = tg & 31;                    // d-pair index for V staging
    const int cc = tg >> 5;                     // 0..3 across the group's 2 waves
    const float SC = 0.18033688f;               // (1/sqrt(64)) * log2(e)

    for (int jj = 0; jj < niter; ++jj) {
        const int j = jj * 4 + g;
        const bool active = (j < ntiles);
        const int kv0 = j * 64;
        __syncthreads();  // prior PV reads of Vt complete
        if (active) {
            // ---- stage V transposed: Vt[d][sp], sp=c*4+n, tau_v=kv0+n*16+c
#pragma unroll
            for (int it = 0; it < 4; ++it) {
                const int c = cc + it * 4;
                unsigned int xv[4];
#pragma unroll
                for (int n = 0; n < 4; ++n)
                    xv[n] = *(const unsigned int*)(xp + hb + 2048 +
                                                   (size_t)((kv0 >> 4) + n) * 3072 +
                                                   c * 64 + 2 * m32);
                unsigned int lo0 = (xv[0] & 0xffffu) | (xv[1] << 16);
                unsigned int lo1 = (xv[2] & 0xffffu) | (xv[3] << 16);
                unsigned int hi0 = (xv[0] >> 16) | (xv[1] & 0xffff0000u);
                unsigned int hi1 = (xv[2] >> 16) | (xv[3] & 0xffff0000u);
                *(uint2*)(Vtg + (2 * m32) * 72 + c * 4) = make_uint2(lo0, lo1);
                *(uint2*)(Vtg + (2 * m32 + 1) * 72 + c * 4) = make_uint2(hi0, hi1);
            }
        }
        __syncthreads();  // Vt staged

        if (active) {
            // ---- S = Q @ K^T; tau_k = kv0 + n*16 + lr
            f32x4 sv[2][4];
#pragma unroll
            for (int mq = 0; mq < 2; ++mq)
#pragma unroll
                for (int n = 0; n < 4; ++n) sv[mq][n] = (f32x4){0.f, 0.f, 0.f, 0.f};
#pragma unroll
            for (int kk = 0; kk < 2; ++kk)
#pragma unroll
                for (int n = 0; n < 4; ++n) {
                    bf16x8 kf = *(const bf16x8*)(xp + hb + 1024 +
                                                 (size_t)((kv0 >> 4) + n) * 3072 +
                                                 lr * 64 + kk * 32 + lg * 8);
#pragma unroll
                    for (int mq = 0; mq < 2; ++mq)
                        sv[mq][n] = __builtin_amdgcn_mfma_f32_16x16x32_bf16(
                            qf[mq][kk], kf, sv[mq][n], 0, 0, 0);
                }
            // ---- scale (exp2 domain) + causal mask (row=lg*4+r, col=lr)
            const bool needMask = (kv0 + 63) > qmin;
#pragma unroll
            for (int mq = 0; mq < 2; ++mq)
#pragma unroll
                for (int n = 0; n < 4; ++n) {
                    sv[mq][n] = sv[mq][n] * SC;
                    if (needMask) {
                        const int col = kv0 + n * 16 + lr;
#pragma unroll
                        for (int r = 0; r < 4; ++r) {
                            const int row = qmin + mq * 16 + lg * 4 + r;
                            if (col > row) sv[mq][n][r] = -1e30f;
                        }
                    }
                }
            // ---- row max over n + 16-lane group
            float rmx[2][4], corr[2][4], rsum[2][4];
#pragma unroll
            for (int mq = 0; mq < 2; ++mq)
#pragma unroll
                for (int r = 0; r < 4; ++r)
                    rmx[mq][r] = fmaxf(fmaxf(sv[mq][0][r], sv[mq][1][r]),
                                       fmaxf(sv[mq][2][r], sv[mq][3][r]));
#pragma unroll
            for (int d = 1; d < 16; d <<= 1)
#pragma unroll
                for (int mq = 0; mq < 2; ++mq)
#pragma unroll
                    for (int r = 0; r < 4; ++r)
                        rmx[mq][r] = fmaxf(rmx[mq][r], __shfl_xor(rmx[mq][r], d, 64));
            // ---- online softmax update (base-2)
#pragma unroll
            for (int mq = 0; mq < 2; ++mq)
#pragma unroll
                for (int r = 0; r < 4; ++r) {
                    float mn = fmaxf(mx[mq][r], rmx[mq][r]);
                    corr[mq][r] = exp2f(mx[mq][r] - mn);
                    mx[mq][r] = mn;
                }
#pragma unroll
            for (int mq = 0; mq < 2; ++mq)
#pragma unroll
                for (int n = 0; n < 4; ++n)
#pragma unroll
                    for (int r = 0; r < 4; ++r)
                        sv[mq][n][r] = exp2f(sv[mq][n][r] - mx[mq][r]);
#pragma unroll
            for (int mq = 0; mq < 2; ++mq)
#pragma unroll
                for (int r = 0; r < 4; ++r)
                    rsum[mq][r] = sv[mq][0][r] + sv[mq][1][r] + sv[mq][2][r] + sv[mq][3][r];
#pragma unroll
            for (int d = 1; d < 16; d <<= 1)
#pragma unroll
                for (int mq = 0; mq < 2; ++mq)
#pragma unroll
                    for (int r = 0; r < 4; ++r)
                        rsum[mq][r] += __shfl_xor(rsum[mq][r], d, 64);
#pragma unroll
            for (int mq = 0; mq < 2; ++mq)
#pragma unroll
                for (int r = 0; r < 4; ++r)
                    ls[mq][r] = ls[mq][r] * corr[mq][r] + rsum[mq][r];
#pragma unroll
            for (int mq = 0; mq < 2; ++mq)
#pragma unroll
                for (int nd = 0; nd < 4; ++nd)
#pragma unroll
                    for (int r = 0; r < 4; ++r) o[mq][nd][r] *= corr[mq][r];
            // ---- pack P -> per-wave LDS, permuted col sp = lr*4 + n (b64)
#pragma unroll
            for (int mq = 0; mq < 2; ++mq)
#pragma unroll
                for (int r = 0; r < 4; ++r) {
                    const int row = mq * 16 + lg * 4 + r;
                    unsigned int u0 = (unsigned)bfu(sv[mq][0][r]) |
                                      ((unsigned)bfu(sv[mq][1][r]) << 16);
                    unsigned int u1 = (unsigned)bfu(sv[mq][2][r]) |
                                      ((unsigned)bfu(sv[mq][3][r]) << 16);
                    *(uint2*)(Plw + row * 72 + lr * 4) = make_uint2(u0, u1);
                }
            asm volatile("s_waitcnt lgkmcnt(0)" ::: "memory");  // wave-internal RAW
            __builtin_amdgcn_sched_barrier(0);
            // ---- O += P @ V (both in permuted-sp contraction order)
#pragma unroll
            for (int kk = 0; kk < 2; ++kk) {
                bf16x8 pa[2];
                pa[0] = *(const bf16x8*)(Plw + (lr) * 72 + kk * 32 + lg * 8);
                pa[1] = *(const bf16x8*)(Plw + (16 + lr) * 72 + kk * 32 + lg * 8);
#pragma unroll
                for (int nd = 0; nd < 4; ++nd) {
                    bf16x8 vb = *(const bf16x8*)(Vtg + (nd * 16 + lr) * 72 + kk * 32 + lg * 8);
                    o[0][nd] = __builtin_amdgcn_mfma_f32_16x16x32_bf16(pa[0], vb, o[0][nd], 0, 0, 0);
                    o[1][nd] = __builtin_amdgcn_mfma_f32_16x16x32_bf16(pa[1], vb, o[1][nd], 0, 0, 0);
                }
            }
        }
    }

    // ---- cross-group merge: (0<-2, 1<-3) then (0<-1); buf lane = 52 f32
    float* buf = (float*)smem;
    auto bufw = [&](int bi) {
        float* q = buf + (size_t)(bi * 64 + l) * 52;
#pragma unroll
        for (int mq = 0; mq < 2; ++mq) {
#pragma unroll
            for (int nd = 0; nd < 4; ++nd)
                *(f32x4*)(q + mq * 16 + nd * 4) = o[mq][nd];
            f32x4 mv = {mx[mq][0], mx[mq][1], mx[mq][2], mx[mq][3]};
            f32x4 lv = {ls[mq][0], ls[mq][1], ls[mq][2], ls[mq][3]};
            *(f32x4*)(q + 32 + mq * 4) = mv;
            *(f32x4*)(q + 40 + mq * 4) = lv;
        }
    };
    auto bufm = [&](int bi) {
        const float* q = buf + (size_t)(bi * 64 + l) * 52;
#pragma unroll
        for (int mq = 0; mq < 2; ++mq) {
            f32x4 mv = *(const f32x4*)(q + 32 + mq * 4);
            f32x4 lv = *(const f32x4*)(q + 40 + mq * 4);
            f32x4 ob[4];
#pragma unroll
            for (int nd = 0; nd < 4; ++nd)
                ob[nd] = *(const f32x4*)(q + mq * 16 + nd * 4);
#pragma unroll
            for (int r = 0; r < 4; ++r) {
                float mn = fmaxf(mx[mq][r], mv[r]);
                float ca = exp2f(mx[mq][r] - mn);
                float cb = exp2f(mv[r] - mn);
                mx[mq][r] = mn;
                ls[mq][r] = ls[mq][r] * ca + lv[r] * cb;
#pragma unroll
                for (int nd = 0; nd < 4; ++nd)
                    o[mq][nd][r] = o[mq][nd][r] * ca + ob[nd][r] * cb;
            }
        }
    };
    __syncthreads();                       // tile-loop LDS use complete
    if (g >= 2) bufw(s * 2 + (g - 2));
    __syncthreads();
    if (g < 2) bufm(s * 2 + g);
    __syncthreads();
    if (g == 1) bufw(s * 2);
    __syncthreads();
    if (g == 0) {
        bufm(s * 2);
        // ---- normalize + store: y[b, tau, h*64 + d] (standard out reshape)
#pragma unroll
        for (int mq = 0; mq < 2; ++mq)
#pragma unroll
            for (int r = 0; r < 4; ++r) {
                const float inv = 1.0f / ls[mq][r];
                const size_t row = rowb + qmin + mq * 16 + lg * 4 + r;
#pragma unroll
                for (int nd = 0; nd < 4; ++nd)
                    y[row * 1024 + h * 64 + nd * 16 + lr] = bfu(o[mq][nd][r] * inv);
            }
    }
}

// ------------------------------- launcher -----------------------------------
extern "C" void kernel_launch(void* const* d_in, const int* in_sizes, int n_in,
                              void* d_out, int out_size, void* d_ws, size_t ws_size,
                              hipStream_t stream) {
    const float* x     = (const float*)d_in[0];
    const float* Wqkv  = (const float*)d_in[1];
    const float* bqkv  = (const float*)d_in[2];
    const float* Wo    = (const float*)d_in[3];
    const float* bo    = (const float*)d_in[4];
    const float* Wfc   = (const float*)d_in[5];
    const float* bfc   = (const float*)d_in[6];
    const float* Wproj = (const float*)d_in[7];
    const float* bproj = (const float*)d_in[8];
    float* out = (float*)d_out;

    char* p = (char*)d_ws;
    unsigned short* xb     = (unsigned short*)(p);
    unsigned short* xpb    = (unsigned short*)(p + (8ull << 20));
    unsigned short* hbuf   = (unsigned short*)(p);              // reuses xb+xp
    unsigned short* ybuf   = (unsigned short*)(p + (32ull << 20));
    float*          x1     = (float*)(p + (40ull << 20));
    unsigned short* x1b    = (unsigned short*)(p + (56ull << 20));
    unsigned short* WqkvT  = (unsigned short*)(p + (64ull << 20));
    unsigned short* WoT    = (unsigned short*)(p + (70ull << 20));
    unsigned short* WfcT   = (unsigned short*)(p + (72ull << 20));
    unsigned short* WprojT = (unsigned short*)(p + (80ull << 20));

    cvt_bf16<<<dim3(2048), 256, 0, stream>>>(x, xb);
    wtrans<<<dim3(96, 32), 256, 0, stream>>>(Wqkv, WqkvT, 1024, 3072);
    wtrans<<<dim3(32, 32), 256, 0, stream>>>(Wo, WoT, 1024, 1024);
    wtrans<<<dim3(128, 32), 256, 0, stream>>>(Wfc, WfcT, 1024, 4096);
    wtrans<<<dim3(32, 128), 256, 0, stream>>>(Wproj, WprojT, 4096, 1024);

    // xp = x @ Wqkv + bqkv
    gemm_bf16<0><<<dim3(24, 32), 256, 0, stream>>>(xb, WqkvT, bqkv, nullptr,
                                                   xpb, nullptr, 4096, 3072, 1024);
    // y = attention(xp): 1024 blocks x 512 thr (8 waves!), 4-way KV split, LPT
    attn<<<dim3(1024), 512, 0, stream>>>(xpb, ybuf);
    // x1 = x + y @ Wo + bo
    gemm_bf16<1><<<dim3(8, 32), 256, 0, stream>>>(ybuf, WoT, bo, x,
                                                  x1b, x1, 4096, 1024, 1024);
    // h = gelu(x1 @ Wfc + bfc)
    gemm_bf16<2><<<dim3(32, 32), 256, 0, stream>>>(x1b, WfcT, bfc, nullptr,
                                                   hbuf, nullptr, 4096, 4096, 1024);
    // out = x1 + h @ Wproj + bproj
    gemm_bf16<3><<<dim3(8, 32), 256, 0, stream>>>(hbuf, WprojT, bproj, x1,
                                                  nullptr, out, 4096, 1024, 4096);
}

// Round 8
// 456.646 us; speedup vs baseline: 1.0676x; 1.0075x over previous
//
#include <hip/hip_runtime.h>

// ---------------------------------------------------------------------------
// Transformer block (B=2, T=2048, C=1024, H=16) on MI355X, bf16 MFMA.
// Reference's quirky reshape: q/k/v = (B,T,C).reshape(B,H,T,hd) DIRECTLY
// => head h attends over xp rows [h*128,(h+1)*128) reinterpreted as 2048
// pseudo-times x 64 ch:  q[b,h,tau,d] = xp[b, h*128 + tau/16, (tau%16)*64+d].
// Output reshape IS standard: y_out[b, tau, h*64+d] = y[b,h,tau,d].
// Workspace layout (88 MB):
//   [0,8M) xb | [8M,32M) xp | [0,32M) h (reuse) | [32M,40M) y
//   [40M,56M) x1 f32 | [56M,64M) x1 bf16 | [64M,88M) transposed weights
// ---------------------------------------------------------------------------

typedef __attribute__((ext_vector_type(8))) short  bf16x8;
typedef __attribute__((ext_vector_type(4))) float  f32x4;
typedef __attribute__((ext_vector_type(8))) unsigned short u16x8;

__device__ __forceinline__ unsigned short bfu(float f) {
    union { float f; unsigned int u; } c; c.f = f;
    unsigned int u = c.u;
    unsigned int r = (u + 0x7fffu + ((u >> 16) & 1u)) >> 16;
    return (unsigned short)r;
}

__device__ __forceinline__ void gload_lds16(const void* g, void* l) {
    __builtin_amdgcn_global_load_lds(
        (const __attribute__((address_space(1))) void*)g,
        (__attribute__((address_space(3))) void*)l, 16, 0, 0);
}

// --------------------------- fp32 -> bf16 convert ---------------------------
__global__ __launch_bounds__(256) void cvt_bf16(const float* __restrict__ in,
                                                unsigned short* __restrict__ out) {
    size_t i = (size_t)blockIdx.x * 256 + threadIdx.x;
    const float4* p = (const float4*)in;
    float4 a = p[2 * i], b = p[2 * i + 1];
    u16x8 v;
    v[0] = bfu(a.x); v[1] = bfu(a.y); v[2] = bfu(a.z); v[3] = bfu(a.w);
    v[4] = bfu(b.x); v[5] = bfu(b.y); v[6] = bfu(b.z); v[7] = bfu(b.w);
    *(u16x8*)(out + 8 * i) = v;
}

// ----------------- weight transpose + convert: W[K][N] -> Wt[N][K] ----------
__global__ __launch_bounds__(256) void wtrans(const float* __restrict__ W,
                                              unsigned short* __restrict__ Wt,
                                              int K, int N) {
    __shared__ float tile[32][33];
    int n0 = blockIdx.x * 32, k0 = blockIdx.y * 32;
    int tx = threadIdx.x & 31, ty = threadIdx.x >> 5;  // ty in 0..7
#pragma unroll
    for (int r = 0; r < 32; r += 8)
        tile[ty + r][tx] = W[(size_t)(k0 + ty + r) * N + n0 + tx];
    __syncthreads();
#pragma unroll
    for (int r = 0; r < 32; r += 8)
        Wt[(size_t)(n0 + ty + r) * K + k0 + tx] = bfu(tile[tx][ty + r]);
}

// --------------------------- GEMM: C = A @ Bt^T -----------------------------
// m97 structure: 128x128 tile, BK=32, 4 waves (2x2), 4x4 16x16x32 frags/wave.
// EPI: 0 = +bias -> bf16 | 1 = +bias+res -> f32 AND bf16 | 2 = +bias,gelu ->
// bf16 | 3 = +bias+res -> f32
template <int EPI>
__global__ __launch_bounds__(256) void gemm_bf16(
    const unsigned short* __restrict__ A, const unsigned short* __restrict__ Bt,
    const float* __restrict__ bias, const float* __restrict__ res,
    unsigned short* __restrict__ outb, float* __restrict__ outf,
    int M, int N, int K) {
    __shared__ __align__(16) unsigned short As[128 * 32];
    __shared__ __align__(16) unsigned short Bs[128 * 32];
    const int t = threadIdx.x;
    const int l = t & 63, w = t >> 6;
    const int lr = l & 15, lg = l >> 4;
    const int brow = blockIdx.y * 128, bcol = blockIdx.x * 128;
    const int wr = (w >> 1) * 64, wc = (w & 1) * 64;

    f32x4 acc[4][4];
#pragma unroll
    for (int m = 0; m < 4; ++m)
#pragma unroll
        for (int n = 0; n < 4; ++n) acc[m][n] = (f32x4){0.f, 0.f, 0.f, 0.f};

    const int ar = t >> 2, ac = (t & 3) * 8;
    const size_t Abase = (size_t)(brow + ar) * K + ac;
    const size_t Bbase = (size_t)(bcol + ar) * K + ac;
    char* la = (char*)As + w * 1024;
    char* lb = (char*)Bs + w * 1024;

    for (int kt = 0; kt < K; kt += 32) {
        gload_lds16(A + Abase + kt, la);
        gload_lds16(A + Abase + (size_t)64 * K + kt, la + 4096);
        gload_lds16(Bt + Bbase + kt, lb);
        gload_lds16(Bt + Bbase + (size_t)64 * K + kt, lb + 4096);
        __syncthreads();

        bf16x8 af[4], bfr[4];
#pragma unroll
        for (int m = 0; m < 4; ++m)
            af[m] = *(const bf16x8*)(As + (wr + m * 16 + lr) * 32 + lg * 8);
#pragma unroll
        for (int n = 0; n < 4; ++n)
            bfr[n] = *(const bf16x8*)(Bs + (wc + n * 16 + lr) * 32 + lg * 8);
#pragma unroll
        for (int m = 0; m < 4; ++m)
#pragma unroll
            for (int n = 0; n < 4; ++n)
                acc[m][n] = __builtin_amdgcn_mfma_f32_16x16x32_bf16(
                    af[m], bfr[n], acc[m][n], 0, 0, 0);
        __syncthreads();
    }

    float bv[4];
#pragma unroll
    for (int n = 0; n < 4; ++n) bv[n] = bias[bcol + wc + n * 16 + lr];
#pragma unroll
    for (int m = 0; m < 4; ++m) {
#pragma unroll
        for (int r = 0; r < 4; ++r) {
            const int row = brow + wr + m * 16 + lg * 4 + r;
#pragma unroll
            for (int n = 0; n < 4; ++n) {
                const int col = bcol + wc + n * 16 + lr;
                const size_t idx = (size_t)row * N + col;
                float v = acc[m][n][r] + bv[n];
                if constexpr (EPI == 0) {
                    outb[idx] = bfu(v);
                } else if constexpr (EPI == 1) {
                    v += res[idx];
                    outf[idx] = v;
                    outb[idx] = bfu(v);
                } else if constexpr (EPI == 2) {
                    float a = 0.7978845608f * (v + 0.044715f * v * v * v);
                    float g = v / (1.0f + __expf(-2.0f * a));  // v*sigmoid(2a)
                    outb[idx] = bfu(g);
                } else {
                    v += res[idx];
                    outf[idx] = v;
                }
            }
        }
    }
}

// ------------------------------ flash attention -----------------------------
// KV-split flash attention. Block = 512 thr = 8 waves. Wave w: qsub s=w&1
// (32 rows), kv-group g=w>>1 (0..3). Group g runs tiles j = g, g+4, ... into
// its own Vt[g]; trip count ceil((qt+1)/4) is block-uniform so barriers are
// legal. End: 2 pairwise (o,m,l) merge rounds through LDS. Worst serial
// depth 8 tiles. Heavy-qt blocks first (LPT). 72KB LDS -> 2 blocks/CU.
// ROUND-6 LESSON: __launch_bounds__(512,4) made hipcc cap VGPR at 64
// (it budgeted 4 BLOCKS/CU = 32 waves) -> ~135MB scratch spill traffic per
// launch (WRITE_SIZE 143MB vs 8MB output). (512,2) -> cap 128, matching the
// LDS-limited 2 blocks/CU residency; live state ~115 regs fits, no spills.
__global__ __launch_bounds__(512, 2) void attn(const unsigned short* __restrict__ xp,
                                               unsigned short* __restrict__ y) {
    __shared__ __align__(16) char smem[73728];
    // tile-loop layout: Vt[4][64*72] u16 (36864B) + Pl[8][32*72] u16 (36864B)
    // merge layout:     buf[4][64 lanes][52 f32] (53248B), overlaid
    const int t = threadIdx.x;
    const int l = t & 63, w = t >> 6;          // 8 waves (512 threads)
    const int s = w & 1, g = w >> 1;           // qsub, kv-group
    const int lr = l & 15, lg = l >> 4;
    const int qt = 31 - (blockIdx.x >> 5);     // heavy blocks first (LPT)
    const int bh = blockIdx.x & 31;
    const int b = bh >> 4, h = bh & 15;
    const size_t hb = ((size_t)b * 2048 + h * 128) * 3072;  // head block base
    const size_t rowb = (size_t)b * 2048;                    // output row base
    const int q0 = qt * 64;
    const int qmin = q0 + s * 32;

    unsigned short* Vtg = (unsigned short*)smem + g * (64 * 72);
    unsigned short* Plw = (unsigned short*)(smem + 36864) + w * (32 * 72);

    // hoist Q fragments: tau_q = qmin + mq*16 + lr -> xp row (qmin>>4)+mq
    bf16x8 qf[2][2];
#pragma unroll
    for (int mq = 0; mq < 2; ++mq)
#pragma unroll
        for (int kk = 0; kk < 2; ++kk)
            qf[mq][kk] = *(const bf16x8*)(xp + hb + (size_t)((qmin >> 4) + mq) * 3072 +
                                          lr * 64 + kk * 32 + lg * 8);

    f32x4 o[2][4];
    float mx[2][4], ls[2][4];
#pragma unroll
    for (int mq = 0; mq < 2; ++mq)
#pragma unroll
        for (int n = 0; n < 4; ++n) o[mq][n] = (f32x4){0.f, 0.f, 0.f, 0.f};
#pragma unroll
    for (int mq = 0; mq < 2; ++mq)
#pragma unroll
        for (int r = 0; r < 4; ++r) { mx[mq][r] = -1e30f; ls[mq][r] = 0.f; }

    const int ntiles = qt + 1;
    const int niter = (qt + 4) >> 2;           // ceil(ntiles/4), block-uniform
    const int tg = s * 64 + l;                  // thread index within kv-group
    const int m32 = tg & 31;                    // d-pair index for V staging
    const int cc = tg >> 5;                     // 0..3 across the group's 2 waves
    const float SC = 0.18033688f;               // (1/sqrt(64)) * log2(e)

    for (int jj = 0; jj < niter; ++jj) {
        const int j = jj * 4 + g;
        const bool active = (j < ntiles);
        const int kv0 = j * 64;
        __syncthreads();  // prior PV reads of Vt complete
        if (active) {
            // ---- stage V transposed: Vt[d][sp], sp=c*4+n, tau_v=kv0+n*16+c
#pragma unroll
            for (int it = 0; it < 4; ++it) {
                const int c = cc + it * 4;
                unsigned int xv[4];
#pragma unroll
                for (int n = 0; n < 4; ++n)
                    xv[n] = *(const unsigned int*)(xp + hb + 2048 +
                                                   (size_t)((kv0 >> 4) + n) * 3072 +
                                                   c * 64 + 2 * m32);
                unsigned int lo0 = (xv[0] & 0xffffu) | (xv[1] << 16);
                unsigned int lo1 = (xv[2] & 0xffffu) | (xv[3] << 16);
                unsigned int hi0 = (xv[0] >> 16) | (xv[1] & 0xffff0000u);
                unsigned int hi1 = (xv[2] >> 16) | (xv[3] & 0xffff0000u);
                *(uint2*)(Vtg + (2 * m32) * 72 + c * 4) = make_uint2(lo0, lo1);
                *(uint2*)(Vtg + (2 * m32 + 1) * 72 + c * 4) = make_uint2(hi0, hi1);
            }
        }
        __syncthreads();  // Vt staged

        if (active) {
            // ---- S = Q @ K^T; tau_k = kv0 + n*16 + lr
            f32x4 sv[2][4];
#pragma unroll
            for (int mq = 0; mq < 2; ++mq)
#pragma unroll
                for (int n = 0; n < 4; ++n) sv[mq][n] = (f32x4){0.f, 0.f, 0.f, 0.f};
#pragma unroll
            for (int kk = 0; kk < 2; ++kk)
#pragma unroll
                for (int n = 0; n < 4; ++n) {
                    bf16x8 kf = *(const bf16x8*)(xp + hb + 1024 +
                                                 (size_t)((kv0 >> 4) + n) * 3072 +
                                                 lr * 64 + kk * 32 + lg * 8);
#pragma unroll
                    for (int mq = 0; mq < 2; ++mq)
                        sv[mq][n] = __builtin_amdgcn_mfma_f32_16x16x32_bf16(
                            qf[mq][kk], kf, sv[mq][n], 0, 0, 0);
                }
            // ---- scale (exp2 domain) + causal mask (row=lg*4+r, col=lr)
            const bool needMask = (kv0 + 63) > qmin;
#pragma unroll
            for (int mq = 0; mq < 2; ++mq)
#pragma unroll
                for (int n = 0; n < 4; ++n) {
                    sv[mq][n] = sv[mq][n] * SC;
                    if (needMask) {
                        const int col = kv0 + n * 16 + lr;
#pragma unroll
                        for (int r = 0; r < 4; ++r) {
                            const int row = qmin + mq * 16 + lg * 4 + r;
                            if (col > row) sv[mq][n][r] = -1e30f;
                        }
                    }
                }
            // ---- row max over n + 16-lane group
            float rmx[2][4], corr[2][4], rsum[2][4];
#pragma unroll
            for (int mq = 0; mq < 2; ++mq)
#pragma unroll
                for (int r = 0; r < 4; ++r)
                    rmx[mq][r] = fmaxf(fmaxf(sv[mq][0][r], sv[mq][1][r]),
                                       fmaxf(sv[mq][2][r], sv[mq][3][r]));
#pragma unroll
            for (int d = 1; d < 16; d <<= 1)
#pragma unroll
                for (int mq = 0; mq < 2; ++mq)
#pragma unroll
                    for (int r = 0; r < 4; ++r)
                        rmx[mq][r] = fmaxf(rmx[mq][r], __shfl_xor(rmx[mq][r], d, 64));
            // ---- online softmax update (base-2)
#pragma unroll
            for (int mq = 0; mq < 2; ++mq)
#pragma unroll
                for (int r = 0; r < 4; ++r) {
                    float mn = fmaxf(mx[mq][r], rmx[mq][r]);
                    corr[mq][r] = exp2f(mx[mq][r] - mn);
                    mx[mq][r] = mn;
                }
#pragma unroll
            for (int mq = 0; mq < 2; ++mq)
#pragma unroll
                for (int n = 0; n < 4; ++n)
#pragma unroll
                    for (int r = 0; r < 4; ++r)
                        sv[mq][n][r] = exp2f(sv[mq][n][r] - mx[mq][r]);
#pragma unroll
            for (int mq = 0; mq < 2; ++mq)
#pragma unroll
                for (int r = 0; r < 4; ++r)
                    rsum[mq][r] = sv[mq][0][r] + sv[mq][1][r] + sv[mq][2][r] + sv[mq][3][r];
#pragma unroll
            for (int d = 1; d < 16; d <<= 1)
#pragma unroll
                for (int mq = 0; mq < 2; ++mq)
#pragma unroll
                    for (int r = 0; r < 4; ++r)
                        rsum[mq][r] += __shfl_xor(rsum[mq][r], d, 64);
#pragma unroll
            for (int mq = 0; mq < 2; ++mq)
#pragma unroll
                for (int r = 0; r < 4; ++r)
                    ls[mq][r] = ls[mq][r] * corr[mq][r] + rsum[mq][r];
#pragma unroll
            for (int mq = 0; mq < 2; ++mq)
#pragma unroll
                for (int nd = 0; nd < 4; ++nd)
#pragma unroll
                    for (int r = 0; r < 4; ++r) o[mq][nd][r] *= corr[mq][r];
            // ---- pack P -> per-wave LDS, permuted col sp = lr*4 + n (b64)
#pragma unroll
            for (int mq = 0; mq < 2; ++mq)
#pragma unroll
                for (int r = 0; r < 4; ++r) {
                    const int row = mq * 16 + lg * 4 + r;
                    unsigned int u0 = (unsigned)bfu(sv[mq][0][r]) |
                                      ((unsigned)bfu(sv[mq][1][r]) << 16);
                    unsigned int u1 = (unsigned)bfu(sv[mq][2][r]) |
                                      ((unsigned)bfu(sv[mq][3][r]) << 16);
                    *(uint2*)(Plw + row * 72 + lr * 4) = make_uint2(u0, u1);
                }
            asm volatile("s_waitcnt lgkmcnt(0)" ::: "memory");  // wave-internal RAW
            __builtin_amdgcn_sched_barrier(0);
            // ---- O += P @ V (both in permuted-sp contraction order)
#pragma unroll
            for (int kk = 0; kk < 2; ++kk) {
                bf16x8 pa[2];
                pa[0] = *(const bf16x8*)(Plw + (lr) * 72 + kk * 32 + lg * 8);
                pa[1] = *(const bf16x8*)(Plw + (16 + lr) * 72 + kk * 32 + lg * 8);
#pragma unroll
                for (int nd = 0; nd < 4; ++nd) {
                    bf16x8 vb = *(const bf16x8*)(Vtg + (nd * 16 + lr) * 72 + kk * 32 + lg * 8);
                    o[0][nd] = __builtin_amdgcn_mfma_f32_16x16x32_bf16(pa[0], vb, o[0][nd], 0, 0, 0);
                    o[1][nd] = __builtin_amdgcn_mfma_f32_16x16x32_bf16(pa[1], vb, o[1][nd], 0, 0, 0);
                }
            }
        }
    }

    // ---- cross-group merge: (0<-2, 1<-3) then (0<-1); buf lane = 52 f32
    float* buf = (float*)smem;
    auto bufw = [&](int bi) {
        float* q = buf + (size_t)(bi * 64 + l) * 52;
#pragma unroll
        for (int mq = 0; mq < 2; ++mq) {
#pragma unroll
            for (int nd = 0; nd < 4; ++nd)
                *(f32x4*)(q + mq * 16 + nd * 4) = o[mq][nd];
            f32x4 mv = {mx[mq][0], mx[mq][1], mx[mq][2], mx[mq][3]};
            f32x4 lv = {ls[mq][0], ls[mq][1], ls[mq][2], ls[mq][3]};
            *(f32x4*)(q + 32 + mq * 4) = mv;
            *(f32x4*)(q + 40 + mq * 4) = lv;
        }
    };
    auto bufm = [&](int bi) {
        const float* q = buf + (size_t)(bi * 64 + l) * 52;
#pragma unroll
        for (int mq = 0; mq < 2; ++mq) {
            f32x4 mv = *(const f32x4*)(q + 32 + mq * 4);
            f32x4 lv = *(const f32x4*)(q + 40 + mq * 4);
            f32x4 ob[4];
#pragma unroll
            for (int nd = 0; nd < 4; ++nd)
                ob[nd] = *(const f32x4*)(q + mq * 16 + nd * 4);
#pragma unroll
            for (int r = 0; r < 4; ++r) {
                float mn = fmaxf(mx[mq][r], mv[r]);
                float ca = exp2f(mx[mq][r] - mn);
                float cb = exp2f(mv[r] - mn);
                mx[mq][r] = mn;
                ls[mq][r] = ls[mq][r] * ca + lv[r] * cb;
#pragma unroll
                for (int nd = 0; nd < 4; ++nd)
                    o[mq][nd][r] = o[mq][nd][r] * ca + ob[nd][r] * cb;
            }
        }
    };
    __syncthreads();                       // tile-loop LDS use complete
    if (g >= 2) bufw(s * 2 + (g - 2));
    __syncthreads();
    if (g < 2) bufm(s * 2 + g);
    __syncthreads();
    if (g == 1) bufw(s * 2);
    __syncthreads();
    if (g == 0) {
        bufm(s * 2);
        // ---- normalize + store: y[b, tau, h*64 + d] (standard out reshape)
#pragma unroll
        for (int mq = 0; mq < 2; ++mq)
#pragma unroll
            for (int r = 0; r < 4; ++r) {
                const float inv = 1.0f / ls[mq][r];
                const size_t row = rowb + qmin + mq * 16 + lg * 4 + r;
#pragma unroll
                for (int nd = 0; nd < 4; ++nd)
                    y[row * 1024 + h * 64 + nd * 16 + lr] = bfu(o[mq][nd][r] * inv);
            }
    }
}

// ------------------------------- launcher -----------------------------------
extern "C" void kernel_launch(void* const* d_in, const int* in_sizes, int n_in,
                              void* d_out, int out_size, void* d_ws, size_t ws_size,
                              hipStream_t stream) {
    const float* x     = (const float*)d_in[0];
    const float* Wqkv  = (const float*)d_in[1];
    const float* bqkv  = (const float*)d_in[2];
    const float* Wo    = (const float*)d_in[3];
    const float* bo    = (const float*)d_in[4];
    const float* Wfc   = (const float*)d_in[5];
    const float* bfc   = (const float*)d_in[6];
    const float* Wproj = (const float*)d_in[7];
    const float* bproj = (const float*)d_in[8];
    float* out = (float*)d_out;

    char* p = (char*)d_ws;
    unsigned short* xb     = (unsigned short*)(p);
    unsigned short* xpb    = (unsigned short*)(p + (8ull << 20));
    unsigned short* hbuf   = (unsigned short*)(p);              // reuses xb+xp
    unsigned short* ybuf   = (unsigned short*)(p + (32ull << 20));
    float*          x1     = (float*)(p + (40ull << 20));
    unsigned short* x1b    = (unsigned short*)(p + (56ull << 20));
    unsigned short* WqkvT  = (unsigned short*)(p + (64ull << 20));
    unsigned short* WoT    = (unsigned short*)(p + (70ull << 20));
    unsigned short* WfcT   = (unsigned short*)(p + (72ull << 20));
    unsigned short* WprojT = (unsigned short*)(p + (80ull << 20));

    cvt_bf16<<<dim3(2048), 256, 0, stream>>>(x, xb);
    wtrans<<<dim3(96, 32), 256, 0, stream>>>(Wqkv, WqkvT, 1024, 3072);
    wtrans<<<dim3(32, 32), 256, 0, stream>>>(Wo, WoT, 1024, 1024);
    wtrans<<<dim3(128, 32), 256, 0, stream>>>(Wfc, WfcT, 1024, 4096);
    wtrans<<<dim3(32, 128), 256, 0, stream>>>(Wproj, WprojT, 4096, 1024);

    // xp = x @ Wqkv + bqkv
    gemm_bf16<0><<<dim3(24, 32), 256, 0, stream>>>(xb, WqkvT, bqkv, nullptr,
                                                   xpb, nullptr, 4096, 3072, 1024);
    // y = attention(xp): 1024 blocks x 512 thr (8 waves), 4-way KV split, LPT
    attn<<<dim3(1024), 512, 0, stream>>>(xpb, ybuf);
    // x1 = x + y @ Wo + bo
    gemm_bf16<1><<<dim3(8, 32), 256, 0, stream>>>(ybuf, WoT, bo, x,
                                                  x1b, x1, 4096, 1024, 1024);
    // h = gelu(x1 @ Wfc + bfc)
    gemm_bf16<2><<<dim3(32, 32), 256, 0, stream>>>(x1b, WfcT, bfc, nullptr,
                                                   hbuf, nullptr, 4096, 4096, 1024);
    // out = x1 + h @ Wproj + bproj
    gemm_bf16<3><<<dim3(8, 32), 256, 0, stream>>>(hbuf, WprojT, bproj, x1,
                                                  nullptr, out, 4096, 1024, 4096);
}

// Round 11
// 426.689 us; speedup vs baseline: 1.1425x; 1.0702x over previous
//
#include <hip/hip_runtime.h>

// ---------------------------------------------------------------------------
// Transformer block (B=2, T=2048, C=1024, H=16) on MI355X, bf16 MFMA.
// Reference's quirky reshape: q/k/v = (B,T,C).reshape(B,H,T,hd) DIRECTLY
// => head h attends over xp rows [h*128,(h+1)*128) reinterpreted as 2048
// pseudo-times x 64 ch:  q[b,h,tau,d] = xp[b, h*128 + tau/16, (tau%16)*64+d].
// Output reshape IS standard: y_out[b, tau, h*64+d] = y[b,h,tau,d].
// Workspace layout (88 MB):
//   [0,8M) xb | [8M,32M) xp | [0,32M) h (reuse) | [32M,40M) y
//   [40M,56M) x1 f32 | [56M,64M) x1 bf16 | [64M,88M) transposed weights
// ---------------------------------------------------------------------------

typedef __attribute__((ext_vector_type(8))) short  bf16x8;
typedef __attribute__((ext_vector_type(4))) float  f32x4;
typedef __attribute__((ext_vector_type(8))) unsigned short u16x8;

__device__ __forceinline__ unsigned short bfu(float f) {
    union { float f; unsigned int u; } c; c.f = f;
    unsigned int u = c.u;
    unsigned int r = (u + 0x7fffu + ((u >> 16) & 1u)) >> 16;
    return (unsigned short)r;
}

__device__ __forceinline__ void gload_lds16(const void* g, void* l) {
    __builtin_amdgcn_global_load_lds(
        (const __attribute__((address_space(1))) void*)g,
        (__attribute__((address_space(3))) void*)l, 16, 0, 0);
}

// --------------------------- fp32 -> bf16 convert ---------------------------
__global__ __launch_bounds__(256) void cvt_bf16(const float* __restrict__ in,
                                                unsigned short* __restrict__ out) {
    size_t i = (size_t)blockIdx.x * 256 + threadIdx.x;
    const float4* p = (const float4*)in;
    float4 a = p[2 * i], b = p[2 * i + 1];
    u16x8 v;
    v[0] = bfu(a.x); v[1] = bfu(a.y); v[2] = bfu(a.z); v[3] = bfu(a.w);
    v[4] = bfu(b.x); v[5] = bfu(b.y); v[6] = bfu(b.z); v[7] = bfu(b.w);
    *(u16x8*)(out + 8 * i) = v;
}

// ----------------- weight transpose + convert: W[K][N] -> Wt[N][K] ----------
__global__ __launch_bounds__(256) void wtrans(const float* __restrict__ W,
                                              unsigned short* __restrict__ Wt,
                                              int K, int N) {
    __shared__ float tile[32][33];
    int n0 = blockIdx.x * 32, k0 = blockIdx.y * 32;
    int tx = threadIdx.x & 31, ty = threadIdx.x >> 5;  // ty in 0..7
#pragma unroll
    for (int r = 0; r < 32; r += 8)
        tile[ty + r][tx] = W[(size_t)(k0 + ty + r) * N + n0 + tx];
    __syncthreads();
#pragma unroll
    for (int r = 0; r < 32; r += 8)
        Wt[(size_t)(n0 + ty + r) * K + k0 + tx] = bfu(tile[tx][ty + r]);
}

// --------------------------- GEMM: C = A @ Bt^T -----------------------------
// m97 structure: 128x128 tile, BK=32, 4 waves (2x2), 4x4 16x16x32 frags/wave.
// EPI: 0 = +bias -> bf16 | 1 = +bias+res -> f32 AND bf16 | 2 = +bias,gelu ->
// bf16 | 3 = +bias+res -> f32
template <int EPI>
__global__ __launch_bounds__(256) void gemm_bf16(
    const unsigned short* __restrict__ A, const unsigned short* __restrict__ Bt,
    const float* __restrict__ bias, const float* __restrict__ res,
    unsigned short* __restrict__ outb, float* __restrict__ outf,
    int M, int N, int K) {
    __shared__ __align__(16) unsigned short As[128 * 32];
    __shared__ __align__(16) unsigned short Bs[128 * 32];
    const int t = threadIdx.x;
    const int l = t & 63, w = t >> 6;
    const int lr = l & 15, lg = l >> 4;
    const int brow = blockIdx.y * 128, bcol = blockIdx.x * 128;
    const int wr = (w >> 1) * 64, wc = (w & 1) * 64;

    f32x4 acc[4][4];
#pragma unroll
    for (int m = 0; m < 4; ++m)
#pragma unroll
        for (int n = 0; n < 4; ++n) acc[m][n] = (f32x4){0.f, 0.f, 0.f, 0.f};

    const int ar = t >> 2, ac = (t & 3) * 8;
    const size_t Abase = (size_t)(brow + ar) * K + ac;
    const size_t Bbase = (size_t)(bcol + ar) * K + ac;
    char* la = (char*)As + w * 1024;
    char* lb = (char*)Bs + w * 1024;

    for (int kt = 0; kt < K; kt += 32) {
        gload_lds16(A + Abase + kt, la);
        gload_lds16(A + Abase + (size_t)64 * K + kt, la + 4096);
        gload_lds16(Bt + Bbase + kt, lb);
        gload_lds16(Bt + Bbase + (size_t)64 * K + kt, lb + 4096);
        __syncthreads();

        bf16x8 af[4], bfr[4];
#pragma unroll
        for (int m = 0; m < 4; ++m)
            af[m] = *(const bf16x8*)(As + (wr + m * 16 + lr) * 32 + lg * 8);
#pragma unroll
        for (int n = 0; n < 4; ++n)
            bfr[n] = *(const bf16x8*)(Bs + (wc + n * 16 + lr) * 32 + lg * 8);
#pragma unroll
        for (int m = 0; m < 4; ++m)
#pragma unroll
            for (int n = 0; n < 4; ++n)
                acc[m][n] = __builtin_amdgcn_mfma_f32_16x16x32_bf16(
                    af[m], bfr[n], acc[m][n], 0, 0, 0);
        __syncthreads();
    }

    float bv[4];
#pragma unroll
    for (int n = 0; n < 4; ++n) bv[n] = bias[bcol + wc + n * 16 + lr];
#pragma unroll
    for (int m = 0; m < 4; ++m) {
#pragma unroll
        for (int r = 0; r < 4; ++r) {
            const int row = brow + wr + m * 16 + lg * 4 + r;
#pragma unroll
            for (int n = 0; n < 4; ++n) {
                const int col = bcol + wc + n * 16 + lr;
                const size_t idx = (size_t)row * N + col;
                float v = acc[m][n][r] + bv[n];
                if constexpr (EPI == 0) {
                    outb[idx] = bfu(v);
                } else if constexpr (EPI == 1) {
                    v += res[idx];
                    outf[idx] = v;
                    outb[idx] = bfu(v);
                } else if constexpr (EPI == 2) {
                    float a = 0.7978845608f * (v + 0.044715f * v * v * v);
                    float g = v / (1.0f + __expf(-2.0f * a));  // v*sigmoid(2a)
                    outb[idx] = bfu(g);
                } else {
                    v += res[idx];
                    outf[idx] = v;
                }
            }
        }
    }
}

// ------------------------------ flash attention -----------------------------
// KV-split attention, FIXED-MAX softmax. Block = 512 thr = 8 waves; wave w:
// qsub s=w&1 (32 rows), kv-group g=w>>1 (0..3); group g runs tiles j=g,g+4,..
// into its own Vt[g]; trip count ceil((qt+1)/4) block-uniform -> barriers ok.
// ROUND-8 LESSON: online-softmax's 64 ds_bpermute shuffles/thread/tile (rmx+
// rsum 4-step chains) + rescale = ~3000 VALU cy/wave-iter (VALUBusy 37%,
// MfmaUtil 5.7%). Replaced by: P = exp2(s*SC - 12) with CONSTANT max shift
// (exact for softmax; scores bounded |s*SC|<~30 so no over/underflow), and
// row-sum ol computed FREE in the MFMA pipe via a ones-column B-fragment
// (ol = mfma(pa, 1s, ol)). Cross-group merge = plain (o,ol) addition.
// Heavy-qt blocks first (LPT). 72KB LDS -> 2 blocks/CU. (512,2) VGPR cap 128.
__global__ __launch_bounds__(512, 2) void attn(const unsigned short* __restrict__ xp,
                                               unsigned short* __restrict__ y) {
    __shared__ __align__(16) char smem[73728];
    // tile-loop layout: Vt[4][64*72] u16 (36864B) + Pl[8][32*72] u16 (36864B)
    // merge layout:     buf[4][64 lanes][40 f32] (40960B), overlaid
    const int t = threadIdx.x;
    const int l = t & 63, w = t >> 6;          // 8 waves (512 threads)
    const int s = w & 1, g = w >> 1;           // qsub, kv-group
    const int lr = l & 15, lg = l >> 4;
    const int qt = 31 - (blockIdx.x >> 5);     // heavy blocks first (LPT)
    const int bh = blockIdx.x & 31;
    const int b = bh >> 4, h = bh & 15;
    const size_t hb = ((size_t)b * 2048 + h * 128) * 3072;  // head block base
    const size_t rowb = (size_t)b * 2048;                    // output row base
    const int q0 = qt * 64;
    const int qmin = q0 + s * 32;

    unsigned short* Vtg = (unsigned short*)smem + g * (64 * 72);
    unsigned short* Plw = (unsigned short*)(smem + 36864) + w * (32 * 72);

    // hoist Q fragments: tau_q = qmin + mq*16 + lr -> xp row (qmin>>4)+mq
    bf16x8 qf[2][2];
#pragma unroll
    for (int mq = 0; mq < 2; ++mq)
#pragma unroll
        for (int kk = 0; kk < 2; ++kk)
            qf[mq][kk] = *(const bf16x8*)(xp + hb + (size_t)((qmin >> 4) + mq) * 3072 +
                                          lr * 64 + kk * 32 + lg * 8);

    // ones B-fragment for the row-sum MFMA (B[k][col] = 1.0 for all k, col)
    bf16x8 onesf;
#pragma unroll
    for (int i = 0; i < 8; ++i) onesf[i] = (short)0x3F80;

    f32x4 o[2][4];
    f32x4 ol[2];  // row-sum accumulator (col-replicated in D layout)
#pragma unroll
    for (int mq = 0; mq < 2; ++mq) {
#pragma unroll
        for (int n = 0; n < 4; ++n) o[mq][n] = (f32x4){0.f, 0.f, 0.f, 0.f};
        ol[mq] = (f32x4){0.f, 0.f, 0.f, 0.f};
    }

    const int ntiles = qt + 1;
    const int niter = (qt + 4) >> 2;           // ceil(ntiles/4), block-uniform
    const int tg = s * 64 + l;                  // thread index within kv-group
    const int m32 = tg & 31;                    // d-pair index for V staging
    const int cc = tg >> 5;                     // 0..3 across the group's 2 waves
    const float SC = 0.18033688f;               // (1/sqrt(64)) * log2(e)

    for (int jj = 0; jj < niter; ++jj) {
        const int j = jj * 4 + g;
        const bool active = (j < ntiles);
        const int kv0 = j * 64;
        __syncthreads();  // prior PV reads of Vt complete
        if (active) {
            // ---- stage V transposed: Vt[d][sp], sp=c*4+n, tau_v=kv0+n*16+c
#pragma unroll
            for (int it = 0; it < 4; ++it) {
                const int c = cc + it * 4;
                unsigned int xv[4];
#pragma unroll
                for (int n = 0; n < 4; ++n)
                    xv[n] = *(const unsigned int*)(xp + hb + 2048 +
                                                   (size_t)((kv0 >> 4) + n) * 3072 +
                                                   c * 64 + 2 * m32);
                unsigned int lo0 = (xv[0] & 0xffffu) | (xv[1] << 16);
                unsigned int lo1 = (xv[2] & 0xffffu) | (xv[3] << 16);
                unsigned int hi0 = (xv[0] >> 16) | (xv[1] & 0xffff0000u);
                unsigned int hi1 = (xv[2] >> 16) | (xv[3] & 0xffff0000u);
                *(uint2*)(Vtg + (2 * m32) * 72 + c * 4) = make_uint2(lo0, lo1);
                *(uint2*)(Vtg + (2 * m32 + 1) * 72 + c * 4) = make_uint2(hi0, hi1);
            }
        }
        __syncthreads();  // Vt staged

        if (active) {
            // ---- S = Q @ K^T; tau_k = kv0 + n*16 + lr
            f32x4 sv[2][4];
#pragma unroll
            for (int mq = 0; mq < 2; ++mq)
#pragma unroll
                for (int n = 0; n < 4; ++n) sv[mq][n] = (f32x4){0.f, 0.f, 0.f, 0.f};
#pragma unroll
            for (int kk = 0; kk < 2; ++kk)
#pragma unroll
                for (int n = 0; n < 4; ++n) {
                    bf16x8 kf = *(const bf16x8*)(xp + hb + 1024 +
                                                 (size_t)((kv0 >> 4) + n) * 3072 +
                                                 lr * 64 + kk * 32 + lg * 8);
#pragma unroll
                    for (int mq = 0; mq < 2; ++mq)
                        sv[mq][n] = __builtin_amdgcn_mfma_f32_16x16x32_bf16(
                            qf[mq][kk], kf, sv[mq][n], 0, 0, 0);
                }
            // ---- P = exp2(s*SC - 12), causal mask (row=lg*4+r, col=lr)
            const bool needMask = (kv0 + 63) > qmin;
#pragma unroll
            for (int mq = 0; mq < 2; ++mq)
#pragma unroll
                for (int n = 0; n < 4; ++n) {
                    sv[mq][n] = sv[mq][n] * SC - 12.0f;   // fma; const max shift
                    if (needMask) {
                        const int col = kv0 + n * 16 + lr;
#pragma unroll
                        for (int r = 0; r < 4; ++r) {
                            const int row = qmin + mq * 16 + lg * 4 + r;
                            if (col > row) sv[mq][n][r] = -1e30f;  // exp2 -> 0
                        }
                    }
#pragma unroll
                    for (int r = 0; r < 4; ++r)
                        sv[mq][n][r] = exp2f(sv[mq][n][r]);
                }
            // ---- pack P -> per-wave LDS, permuted col sp = lr*4 + n (b64)
#pragma unroll
            for (int mq = 0; mq < 2; ++mq)
#pragma unroll
                for (int r = 0; r < 4; ++r) {
                    const int row = mq * 16 + lg * 4 + r;
                    unsigned int u0 = (unsigned)bfu(sv[mq][0][r]) |
                                      ((unsigned)bfu(sv[mq][1][r]) << 16);
                    unsigned int u1 = (unsigned)bfu(sv[mq][2][r]) |
                                      ((unsigned)bfu(sv[mq][3][r]) << 16);
                    *(uint2*)(Plw + row * 72 + lr * 4) = make_uint2(u0, u1);
                }
            asm volatile("s_waitcnt lgkmcnt(0)" ::: "memory");  // wave-internal RAW
            __builtin_amdgcn_sched_barrier(0);
            // ---- O += P @ V; OL += P @ 1 (row-sum, free on MFMA pipe)
#pragma unroll
            for (int kk = 0; kk < 2; ++kk) {
                bf16x8 pa[2];
                pa[0] = *(const bf16x8*)(Plw + (lr) * 72 + kk * 32 + lg * 8);
                pa[1] = *(const bf16x8*)(Plw + (16 + lr) * 72 + kk * 32 + lg * 8);
#pragma unroll
                for (int nd = 0; nd < 4; ++nd) {
                    bf16x8 vb = *(const bf16x8*)(Vtg + (nd * 16 + lr) * 72 + kk * 32 + lg * 8);
                    o[0][nd] = __builtin_amdgcn_mfma_f32_16x16x32_bf16(pa[0], vb, o[0][nd], 0, 0, 0);
                    o[1][nd] = __builtin_amdgcn_mfma_f32_16x16x32_bf16(pa[1], vb, o[1][nd], 0, 0, 0);
                }
                ol[0] = __builtin_amdgcn_mfma_f32_16x16x32_bf16(pa[0], onesf, ol[0], 0, 0, 0);
                ol[1] = __builtin_amdgcn_mfma_f32_16x16x32_bf16(pa[1], onesf, ol[1], 0, 0, 0);
            }
        }
    }

    // ---- cross-group merge: plain ADDITION of (o, ol): (0<-2,1<-3) then 0<-1
    float* buf = (float*)smem;
    auto bufw = [&](int bi) {
        float* q = buf + (size_t)(bi * 64 + l) * 40;
#pragma unroll
        for (int mq = 0; mq < 2; ++mq) {
#pragma unroll
            for (int nd = 0; nd < 4; ++nd)
                *(f32x4*)(q + mq * 16 + nd * 4) = o[mq][nd];
            *(f32x4*)(q + 32 + mq * 4) = ol[mq];
        }
    };
    auto bufm = [&](int bi) {
        const float* q = buf + (size_t)(bi * 64 + l) * 40;
#pragma unroll
        for (int mq = 0; mq < 2; ++mq) {
#pragma unroll
            for (int nd = 0; nd < 4; ++nd)
                o[mq][nd] += *(const f32x4*)(q + mq * 16 + nd * 4);
            ol[mq] += *(const f32x4*)(q + 32 + mq * 4);
        }
    };
    __syncthreads();                       // tile-loop LDS use complete
    if (g >= 2) bufw(s * 2 + (g - 2));
    __syncthreads();
    if (g < 2) bufm(s * 2 + g);
    __syncthreads();
    if (g == 1) bufw(s * 2);
    __syncthreads();
    if (g == 0) {
        bufm(s * 2);
        // ---- normalize + store: y[b, tau, h*64 + d] (standard out reshape)
#pragma unroll
        for (int mq = 0; mq < 2; ++mq)
#pragma unroll
            for (int r = 0; r < 4; ++r) {
                const float inv = 1.0f / ol[mq][r];
                const size_t row = rowb + qmin + mq * 16 + lg * 4 + r;
#pragma unroll
                for (int nd = 0; nd < 4; ++nd)
                    y[row * 1024 + h * 64 + nd * 16 + lr] = bfu(o[mq][nd][r] * inv);
            }
    }
}

// ------------------------------- launcher -----------------------------------
extern "C" void kernel_launch(void* const* d_in, const int* in_sizes, int n_in,
                              void* d_out, int out_size, void* d_ws, size_t ws_size,
                              hipStream_t stream) {
    const float* x     = (const float*)d_in[0];
    const float* Wqkv  = (const float*)d_in[1];
    const float* bqkv  = (const float*)d_in[2];
    const float* Wo    = (const float*)d_in[3];
    const float* bo    = (const float*)d_in[4];
    const float* Wfc   = (const float*)d_in[5];
    const float* bfc   = (const float*)d_in[6];
    const float* Wproj = (const float*)d_in[7];
    const float* bproj = (const float*)d_in[8];
    float* out = (float*)d_out;

    char* p = (char*)d_ws;
    unsigned short* xb     = (unsigned short*)(p);
    unsigned short* xpb    = (unsigned short*)(p + (8ull << 20));
    unsigned short* hbuf   = (unsigned short*)(p);              // reuses xb+xp
    unsigned short* ybuf   = (unsigned short*)(p + (32ull << 20));
    float*          x1     = (float*)(p + (40ull << 20));
    unsigned short* x1b    = (unsigned short*)(p + (56ull << 20));
    unsigned short* WqkvT  = (unsigned short*)(p + (64ull << 20));
    unsigned short* WoT    = (unsigned short*)(p + (70ull << 20));
    unsigned short* WfcT   = (unsigned short*)(p + (72ull << 20));
    unsigned short* WprojT = (unsigned short*)(p + (80ull << 20));

    cvt_bf16<<<dim3(2048), 256, 0, stream>>>(x, xb);
    wtrans<<<dim3(96, 32), 256, 0, stream>>>(Wqkv, WqkvT, 1024, 3072);
    wtrans<<<dim3(32, 32), 256, 0, stream>>>(Wo, WoT, 1024, 1024);
    wtrans<<<dim3(128, 32), 256, 0, stream>>>(Wfc, WfcT, 1024, 4096);
    wtrans<<<dim3(32, 128), 256, 0, stream>>>(Wproj, WprojT, 4096, 1024);

    // xp = x @ Wqkv + bqkv
    gemm_bf16<0><<<dim3(24, 32), 256, 0, stream>>>(xb, WqkvT, bqkv, nullptr,
                                                   xpb, nullptr, 4096, 3072, 1024);
    // y = attention(xp): 1024 blocks x 512 thr, fixed-max softmax, LPT
    attn<<<dim3(1024), 512, 0, stream>>>(xpb, ybuf);
    // x1 = x + y @ Wo + bo
    gemm_bf16<1><<<dim3(8, 32), 256, 0, stream>>>(ybuf, WoT, bo, x,
                                                  x1b, x1, 4096, 1024, 1024);
    // h = gelu(x1 @ Wfc + bfc)
    gemm_bf16<2><<<dim3(32, 32), 256, 0, stream>>>(x1b, WfcT, bfc, nullptr,
                                                   hbuf, nullptr, 4096, 4096, 1024);
    // out = x1 + h @ Wproj + bproj
    gemm_bf16<3><<<dim3(8, 32), 256, 0, stream>>>(hbuf, WprojT, bproj, x1,
                                                  nullptr, out, 4096, 1024, 4096);
}